// Round 5
// baseline (52.069 us; speedup 1.0000x reference)
//
#include <hip/hip_runtime.h>

#define TLEN 4096
#define NT 256
#define NGRP (TLEN / 4)     // 1024 groups of 4 consecutive outputs
#define GPT (NGRP / NT)     // 4 groups per thread

typedef float f32x4 __attribute__((ext_vector_type(4)));

__device__ __forceinline__ f32x4 ldv4(const float* p) {
    return *reinterpret_cast<const f32x4*>(p);
}

__global__ __launch_bounds__(NT, 5) void swt_db4_l3_kernel(
    const float* __restrict__ x,
    const float* __restrict__ lo_g,
    const float* __restrict__ hi_g,
    float* __restrict__ out)
{
    __shared__ float bufA[TLEN];
    __shared__ float bufB[TLEN];

    const int row = blockIdx.x;
    const int tid = threadIdx.x;

    float lo[8], hi[8];   // uniform addresses -> SGPR via s_load
#pragma unroll
    for (int j = 0; j < 8; ++j) { lo[j] = lo_g[j]; hi[j] = hi_g[j]; }

    const float* xr = x + (size_t)row * TLEN;

    // Stage whole row into LDS (coalesced float4).
#pragma unroll
    for (int k = 0; k < 4; ++k) {
        int idx = (tid + k * NT) * 4;
        *reinterpret_cast<f32x4*>(&bufA[idx]) = ldv4(xr + idx);
    }
    __syncthreads();

    float D1[GPT][4], D2[GPT][4];

    // ---- Level 1: dil=1. window [4g-4, 4g+12), idx = i+8-j ----
#pragma unroll
    for (int k = 0; k < GPT; ++k) {
        int g = tid + k * NT;
        float a[4] = {0,0,0,0}, d[4] = {0,0,0,0};
        if (g >= 1 && g <= 1021) {
            float w[16];
#pragma unroll
            for (int m = 0; m < 4; ++m)
                *reinterpret_cast<f32x4*>(&w[4*m]) = ldv4(&bufA[4*g - 4 + 4*m]);
#pragma unroll
            for (int j = 0; j < 8; ++j)
#pragma unroll
                for (int i = 0; i < 4; ++i) {
                    float v = w[i + 8 - j];
                    a[i] = fmaf(lo[j], v, a[i]);
                    d[i] = fmaf(hi[j], v, d[i]);
                }
        } else {
#pragma unroll
            for (int i = 0; i < 4; ++i) {
                int t = 4*g + i;
#pragma unroll
                for (int j = 0; j < 8; ++j) {
                    float v = bufA[(t + (4 - j)) & (TLEN - 1)];
                    a[i] = fmaf(lo[j], v, a[i]);
                    d[i] = fmaf(hi[j], v, d[i]);
                }
            }
        }
        f32x4 av; av.x = a[0]; av.y = a[1]; av.z = a[2]; av.w = a[3];
        *reinterpret_cast<f32x4*>(&bufB[4*g]) = av;
#pragma unroll
        for (int i = 0; i < 4; ++i) D1[k][i] = d[i];
    }
    __syncthreads();

    // ---- Level 2: dil=2. window [4g-8, 4g+12), idx = i+16-2j ----
#pragma unroll
    for (int k = 0; k < GPT; ++k) {
        int g = tid + k * NT;
        float a[4] = {0,0,0,0}, d[4] = {0,0,0,0};
        if (g >= 2 && g <= 1021) {
            float w[20];
#pragma unroll
            for (int m = 0; m < 5; ++m)
                *reinterpret_cast<f32x4*>(&w[4*m]) = ldv4(&bufB[4*g - 8 + 4*m]);
#pragma unroll
            for (int j = 0; j < 8; ++j)
#pragma unroll
                for (int i = 0; i < 4; ++i) {
                    float v = w[i + 16 - 2*j];
                    a[i] = fmaf(lo[j], v, a[i]);
                    d[i] = fmaf(hi[j], v, d[i]);
                }
        } else {
#pragma unroll
            for (int i = 0; i < 4; ++i) {
                int t = 4*g + i;
#pragma unroll
                for (int j = 0; j < 8; ++j) {
                    float v = bufB[(t + (4 - j) * 2) & (TLEN - 1)];
                    a[i] = fmaf(lo[j], v, a[i]);
                    d[i] = fmaf(hi[j], v, d[i]);
                }
            }
        }
        f32x4 av; av.x = a[0]; av.y = a[1]; av.z = a[2]; av.w = a[3];
        *reinterpret_cast<f32x4*>(&bufA[4*g]) = av;   // bufA fully consumed pre-barrier
#pragma unroll
        for (int i = 0; i < 4; ++i) D2[k][i] = d[i];
    }
    __syncthreads();

    // ---- Level 3: dil=4. window [4g-12, 4g+20), idx = i+28-4j; store ----
    f32x4* outr = reinterpret_cast<f32x4*>(out + (size_t)row * TLEN * 4);
#pragma unroll
    for (int k = 0; k < GPT; ++k) {
        int g = tid + k * NT;
        float a[4] = {0,0,0,0}, d[4] = {0,0,0,0};
        if (g >= 3 && g <= 1019) {
            float w[32];
#pragma unroll
            for (int m = 0; m < 8; ++m)
                *reinterpret_cast<f32x4*>(&w[4*m]) = ldv4(&bufA[4*g - 12 + 4*m]);
#pragma unroll
            for (int j = 0; j < 8; ++j)
#pragma unroll
                for (int i = 0; i < 4; ++i) {
                    float v = w[i + 28 - 4*j];
                    a[i] = fmaf(lo[j], v, a[i]);
                    d[i] = fmaf(hi[j], v, d[i]);
                }
        } else {
#pragma unroll
            for (int i = 0; i < 4; ++i) {
                int t = 4*g + i;
#pragma unroll
                for (int j = 0; j < 8; ++j) {
                    float v = bufA[(t + (4 - j) * 4) & (TLEN - 1)];
                    a[i] = fmaf(lo[j], v, a[i]);
                    d[i] = fmaf(hi[j], v, d[i]);
                }
            }
        }
#pragma unroll
        for (int i = 0; i < 4; ++i) {
            f32x4 v;
            v.x = a[i]; v.y = d[i]; v.z = D2[k][i]; v.w = D1[k][i];
            outr[4*g + i] = v;
        }
    }
}

extern "C" void kernel_launch(void* const* d_in, const int* in_sizes, int n_in,
                              void* d_out, int out_size, void* d_ws, size_t ws_size,
                              hipStream_t stream) {
    const float* x  = (const float*)d_in[0];
    const float* lo = (const float*)d_in[1];
    const float* hi = (const float*)d_in[2];
    float* out = (float*)d_out;

    const int rows = 64 * 32;   // B * N
    swt_db4_l3_kernel<<<dim3(rows), dim3(NT), 0, stream>>>(x, lo, hi, out);
}

// Round 6
// 32.765 us; speedup vs baseline: 1.5891x; 1.5891x over previous
//
#include <hip/hip_runtime.h>

#define TLEN 4096
#define NT 256
#define PER 16                 // elements per thread
#define SH 12                  // left halo (3*max_dil)
#define RH 16                  // right halo (4*max_dil)
#define BUFLEN (SH + TLEN + RH)

typedef float f32x4 __attribute__((ext_vector_type(4)));
typedef float f32x2 __attribute__((ext_vector_type(2)));

__device__ __forceinline__ f32x4 ldv4(const float* p) {
    return *reinterpret_cast<const f32x4*>(p);
}

__global__ __launch_bounds__(NT, 4) void swt_db4_l3_kernel(
    const float* __restrict__ x,
    const float* __restrict__ lo_g,
    const float* __restrict__ hi_g,
    float* __restrict__ out)
{
    __shared__ float bufA[BUFLEN];   // x, then A2
    __shared__ float bufB[BUFLEN];   // A1

    const int row = blockIdx.x;
    const int tid = threadIdx.x;

    // packed (lo, hi) filter pairs; uniform -> scalar regs
    f32x2 c[8];
#pragma unroll
    for (int j = 0; j < 8; ++j) { c[j].x = lo_g[j]; c[j].y = hi_g[j]; }

    const float* xr = x + (size_t)row * TLEN;

    // ---- Stage x into bufA with wrap halos (float4, coalesced) ----
#pragma unroll
    for (int k = 0; k < 4; ++k) {
        int idx = (tid + k * NT) * 4;
        f32x4 v = ldv4(xr + idx);
        *reinterpret_cast<f32x4*>(&bufA[SH + idx]) = v;
        if (k == 0 && tid < 4)                      // x[0..15] -> right halo
            *reinterpret_cast<f32x4*>(&bufA[SH + TLEN + idx]) = v;
        if (k == 3 && idx >= TLEN - SH)             // x[4084..4095] -> left halo
            *reinterpret_cast<f32x4*>(&bufA[idx - (TLEN - SH)]) = v;
    }
    __syncthreads();

    float D1[PER], D2[PER];

    // ---- Level 1: dil=1, bufA -> bufB (+halos), D1 regs ----
#pragma unroll
    for (int k = 0; k < PER; ++k) {
        int t = tid + k * NT;
        const float* s = &bufA[t + SH];
        f32x2 acc; acc.x = 0.f; acc.y = 0.f;
#pragma unroll
        for (int j = 0; j < 8; ++j) {
            float v = s[(4 - j)];
            f32x2 vv; vv.x = v; vv.y = v;
            acc = __builtin_elementwise_fma(c[j], vv, acc);
        }
        bufB[t + SH] = acc.x;
        if (k == 0 && tid < RH)           bufB[t + SH + TLEN] = acc.x;
        if (k == PER - 1 && t >= TLEN - SH) bufB[t + SH - TLEN] = acc.x;
        D1[k] = acc.y;
    }
    __syncthreads();

    // ---- Level 2: dil=2, bufB -> bufA (+halos), D2 regs ----
#pragma unroll
    for (int k = 0; k < PER; ++k) {
        int t = tid + k * NT;
        const float* s = &bufB[t + SH];
        f32x2 acc; acc.x = 0.f; acc.y = 0.f;
#pragma unroll
        for (int j = 0; j < 8; ++j) {
            float v = s[(4 - j) * 2];
            f32x2 vv; vv.x = v; vv.y = v;
            acc = __builtin_elementwise_fma(c[j], vv, acc);
        }
        bufA[t + SH] = acc.x;             // x fully consumed in level 1
        if (k == 0 && tid < RH)           bufA[t + SH + TLEN] = acc.x;
        if (k == PER - 1 && t >= TLEN - SH) bufA[t + SH - TLEN] = acc.x;
        D2[k] = acc.y;
    }
    __syncthreads();

    // ---- Level 3: dil=4, bufA -> regs; fused store ----
    f32x4* outr = reinterpret_cast<f32x4*>(out + (size_t)row * TLEN * 4);
#pragma unroll
    for (int k = 0; k < PER; ++k) {
        int t = tid + k * NT;
        const float* s = &bufA[t + SH];
        f32x2 acc; acc.x = 0.f; acc.y = 0.f;
#pragma unroll
        for (int j = 0; j < 8; ++j) {
            float v = s[(4 - j) * 4];
            f32x2 vv; vv.x = v; vv.y = v;
            acc = __builtin_elementwise_fma(c[j], vv, acc);
        }
        f32x4 o;
        o.x = acc.x;   // A3
        o.y = acc.y;   // D3
        o.z = D2[k];
        o.w = D1[k];
        outr[t] = o;
    }
}

extern "C" void kernel_launch(void* const* d_in, const int* in_sizes, int n_in,
                              void* d_out, int out_size, void* d_ws, size_t ws_size,
                              hipStream_t stream) {
    const float* x  = (const float*)d_in[0];
    const float* lo = (const float*)d_in[1];
    const float* hi = (const float*)d_in[2];
    float* out = (float*)d_out;

    const int rows = 64 * 32;   // B * N
    swt_db4_l3_kernel<<<dim3(rows), dim3(NT), 0, stream>>>(x, lo, hi, out);
}